// Round 1
// baseline (476.600 us; speedup 1.0000x reference)
//
#include <hip/hip_runtime.h>
#include <hip/hip_bf16.h>

// out[token][d] = W[idx[token]][d] + b[d]
// token in [0, 8192), d in [0, 2048). All fp32.
// 2048 floats = 512 float4 per row; 256 threads x 2 float4 each.

__global__ __launch_bounds__(256)
void embed_gather_kernel(const int* __restrict__ idx,
                         const float4* __restrict__ W,
                         const float4* __restrict__ b,
                         float4* __restrict__ out,
                         int n_tokens) {
    const int token = blockIdx.x;
    if (token >= n_tokens) return;
    const int row = idx[token];  // block-uniform -> scalar load
    const float4* __restrict__ src = W + (size_t)row * 512;
    float4* __restrict__ dst = out + (size_t)token * 512;
    const int t = threadIdx.x;

#pragma unroll
    for (int k = 0; k < 2; ++k) {
        const int j = t + (k << 8);
        float4 v = src[j];
        const float4 bb = b[j];
        v.x += bb.x;
        v.y += bb.y;
        v.z += bb.z;
        v.w += bb.w;
        dst[j] = v;
    }
}

extern "C" void kernel_launch(void* const* d_in, const int* in_sizes, int n_in,
                              void* d_out, int out_size, void* d_ws, size_t ws_size,
                              hipStream_t stream) {
    const int*    x = (const int*)d_in[0];    // [4, 2048] token ids
    const float4* W = (const float4*)d_in[1]; // [50257, 2048] fp32 -> 512 float4/row
    const float4* b = (const float4*)d_in[2]; // [2048] fp32 -> 512 float4
    float4* out = (float4*)d_out;             // [4, 2048, 2048] fp32

    const int n_tokens = in_sizes[0];         // 8192
    embed_gather_kernel<<<n_tokens, 256, 0, stream>>>(x, W, b, out, n_tokens);
}